// Round 1
// baseline (8687.198 us; speedup 1.0000x reference)
//
#include <hip/hip_runtime.h>
#include <hip/hip_bf16.h>
#include <math.h>

#define Bsz 16
#define Ntok 785
#define Cdim 768
#define Hn 12
#define HD 64
#define Ttok 797   // Ntok + Hn
#define K3C 2304   // 3*Cdim
#define LN_EPS 1e-5f

__device__ inline float wave_sum(float v) {
    #pragma unroll
    for (int off = 32; off; off >>= 1) v += __shfl_xor(v, off, 64);
    return v;
}

// ---------------- column mean over tokens (two-stage, deterministic) -------
__global__ void colmean_partial(const float* __restrict__ x, float* __restrict__ partial) {
    int b = blockIdx.x, ch = blockIdx.y, t = threadIdx.x;
    int n0 = ch * 50, n1 = min(Ntok, n0 + 50);
    float s0 = 0.f, s1 = 0.f, s2 = 0.f;
    for (int n = n0; n < n1; ++n) {
        const float* row = x + ((size_t)b * Ntok + n) * Cdim;
        s0 += row[t]; s1 += row[t + 256]; s2 += row[t + 512];
    }
    float* p = partial + ((size_t)b * 16 + ch) * Cdim;
    p[t] = s0; p[t + 256] = s1; p[t + 512] = s2;
}

__global__ void colmean_reduce(const float* __restrict__ partial, float* __restrict__ xh) {
    int b = blockIdx.x, t = threadIdx.x;
    #pragma unroll
    for (int i = 0; i < 3; ++i) {
        int c = t + i * 256;
        float s = 0.f;
        for (int ch = 0; ch < 16; ++ch) s += partial[((size_t)b * 16 + ch) * Cdim + c];
        xh[(size_t)b * Cdim + c] = s * (1.0f / (float)Ntok);
    }
}

// ------------- head tokens: proj + LayerNorm(hd) + GELU + pos -> xa[N..] ---
__global__ void headtok_kernel(const float* __restrict__ xh, const float* __restrict__ htp_w,
                               const float* __restrict__ htp_b, const float* __restrict__ ln_g,
                               const float* __restrict__ ln_b, const float* __restrict__ pos,
                               float* __restrict__ xa) {
    int blk = blockIdx.x;               // b*H*H + h*H + h2
    int b  = blk / (Hn * Hn);
    int rem = blk % (Hn * Hn);
    int h  = rem / Hn;
    int h2 = rem % Hn;
    int lane = threadIdx.x;             // 0..63 == d within hd
    int c = h2 * HD + lane;

    float acc = htp_b[c];
    const float* xrow = xh + (size_t)b * Cdim + h * HD;
    #pragma unroll 8
    for (int d = 0; d < HD; ++d) acc += xrow[d] * htp_w[(size_t)d * Cdim + c];

    // LayerNorm over the 64 lanes
    float mu = wave_sum(acc) * (1.0f / 64.0f);
    float diff = acc - mu;
    float var = wave_sum(diff * diff) * (1.0f / 64.0f);
    float y = diff * rsqrtf(var + LN_EPS) * ln_g[lane] + ln_b[lane];
    // exact GELU
    float g = 0.5f * y * (1.0f + erff(y * 0.70710678118654752f));
    float v = g + pos[(size_t)h * Cdim + c];
    xa[((size_t)b * Ttok + Ntok + h) * Cdim + c] = v;
}

// -------------------- copy x into xa rows [0, N) ---------------------------
__global__ void copy_x_to_xa(const float4* __restrict__ x, float4* __restrict__ xa) {
    const int C4 = Cdim / 4;
    int total = Bsz * Ntok * C4;
    for (int i = blockIdx.x * blockDim.x + threadIdx.x; i < total; i += gridDim.x * blockDim.x) {
        int row = i / C4, c4 = i - row * C4;
        int b = row / Ntok, n = row - b * Ntok;
        xa[((size_t)b * Ttok + n) * C4 + c4] = x[i];
    }
}

// -------------------- fp32 tiled GEMM: Out = A(MxK) @ W(KxN) [+bias] -------
// mode 0: row-major MxN output. mode 1: scatter to qkv buffer (3,B,H,T,hd).
__global__ void gemm_kernel(const float* __restrict__ A, const float* __restrict__ W,
                            const float* __restrict__ bias, float* __restrict__ Out,
                            int M, int Nn, int K, int mode) {
    __shared__ float As[16][68];
    __shared__ float Bs[16][68];
    int tid = threadIdx.x;
    int tx = tid & 15, ty = tid >> 4;
    int mBase = blockIdx.x * 64, nBase = blockIdx.y * 64;

    float acc[4][4];
    #pragma unroll
    for (int i = 0; i < 4; ++i)
        #pragma unroll
        for (int j = 0; j < 4; ++j) acc[i][j] = 0.f;

    int aRow = tid >> 2;            // 0..63
    int aK4  = (tid & 3) * 4;       // 0,4,8,12
    int bK   = tid >> 4;            // 0..15
    int bN4  = (tid & 15) * 4;

    for (int k0 = 0; k0 < K; k0 += 16) {
        int gm = mBase + aRow;
        float4 av = make_float4(0.f, 0.f, 0.f, 0.f);
        if (gm < M) av = *reinterpret_cast<const float4*>(&A[(size_t)gm * K + k0 + aK4]);
        As[aK4 + 0][aRow] = av.x; As[aK4 + 1][aRow] = av.y;
        As[aK4 + 2][aRow] = av.z; As[aK4 + 3][aRow] = av.w;
        float4 bv = *reinterpret_cast<const float4*>(&W[(size_t)(k0 + bK) * Nn + nBase + bN4]);
        *reinterpret_cast<float4*>(&Bs[bK][bN4]) = bv;
        __syncthreads();
        #pragma unroll
        for (int kk = 0; kk < 16; ++kk) {
            float4 a4 = *reinterpret_cast<const float4*>(&As[kk][ty * 4]);
            float4 b4 = *reinterpret_cast<const float4*>(&Bs[kk][tx * 4]);
            float a[4] = {a4.x, a4.y, a4.z, a4.w};
            float bb[4] = {b4.x, b4.y, b4.z, b4.w};
            #pragma unroll
            for (int i = 0; i < 4; ++i)
                #pragma unroll
                for (int j = 0; j < 4; ++j) acc[i][j] = fmaf(a[i], bb[j], acc[i][j]);
        }
        __syncthreads();
    }

    #pragma unroll
    for (int i = 0; i < 4; ++i) {
        int gm = mBase + ty * 4 + i;
        if (gm >= M) continue;
        #pragma unroll
        for (int j = 0; j < 4; ++j) {
            int gn = nBase + tx * 4 + j;
            float v = acc[i][j] + (bias ? bias[gn] : 0.f);
            if (mode == 0) {
                Out[(size_t)gm * Nn + gn] = v;
            } else {
                int s = gn / Cdim;
                int hc = gn - s * Cdim;
                int h = hc >> 6, d = hc & 63;
                int b = gm / Ttok, t = gm - b * Ttok;
                Out[(((size_t)(s * Bsz + b) * Hn + h) * Ttok + t) * HD + d] = v;
            }
        }
    }
}

// -------------------- attention: one wave per q-row, online softmax --------
__global__ void attn_kernel(const float* __restrict__ Qb, const float* __restrict__ Kb,
                            const float* __restrict__ Vb, float* __restrict__ Ob) {
    const int nQB = 200; // ceil(T/4)
    int bh = blockIdx.x / nQB;
    int qb = blockIdx.x % nQB;
    int w = threadIdx.x >> 6;
    int lane = threadIdx.x & 63;
    int r = qb * 4 + w;
    if (r >= Ttok) return;

    const float* Q = Qb + ((size_t)bh * Ttok + r) * HD;
    const float* Kp = Kb + (size_t)bh * Ttok * HD;
    const float* Vp = Vb + (size_t)bh * Ttok * HD;
    float qd = Q[lane];
    float m = -1e30f, l = 0.f, acc = 0.f;
    for (int k = 0; k < Ttok; ++k) {
        float kv = Kp[k * HD + lane];
        float s = wave_sum(qd * kv) * 0.125f;
        float vv = Vp[k * HD + lane];
        float mn = fmaxf(m, s);
        float corr = __expf(m - mn);
        float p = __expf(s - mn);
        l = l * corr + p;
        acc = acc * corr + p * vv;
        m = mn;
    }
    int b = bh / Hn, h = bh % Hn;
    Ob[((size_t)b * Ttok + r) * Cdim + h * HD + lane] = acc / l;
}

// -------------------- epilogue: cls row + copy rows 1..N-1 -----------------
__global__ void cls_kernel(const float* __restrict__ out_full, float* __restrict__ out) {
    int b = blockIdx.x, t = threadIdx.x;
    #pragma unroll
    for (int i = 0; i < 3; ++i) {
        int c = t + i * 256;
        float s = out_full[((size_t)b * Ttok) * Cdim + c];
        float hs = 0.f;
        #pragma unroll
        for (int h = 0; h < Hn; ++h)
            hs += out_full[((size_t)b * Ttok + Ntok + h) * Cdim + c];
        out[((size_t)b * Ntok) * Cdim + c] = s + hs * (1.0f / (float)Hn);
    }
}

__global__ void final_copy(const float4* __restrict__ out_full, float4* __restrict__ out) {
    const int C4 = Cdim / 4;
    int total = Bsz * (Ntok - 1) * C4;
    for (int i = blockIdx.x * blockDim.x + threadIdx.x; i < total; i += gridDim.x * blockDim.x) {
        int row = i / C4, c4 = i - row * C4;
        int b = row / (Ntok - 1), n = 1 + row - b * (Ntok - 1);
        out[((size_t)b * Ntok + n) * C4 + c4] = out_full[((size_t)b * Ttok + n) * C4 + c4];
    }
}

extern "C" void kernel_launch(void* const* d_in, const int* in_sizes, int n_in,
                              void* d_out, int out_size, void* d_ws, size_t ws_size,
                              hipStream_t stream) {
    const float* x      = (const float*)d_in[0];
    const float* qkv_w  = (const float*)d_in[1];
    const float* proj_w = (const float*)d_in[2];
    const float* proj_b = (const float*)d_in[3];
    const float* htp_w  = (const float*)d_in[4];
    const float* htp_b  = (const float*)d_in[5];
    const float* ln_g   = (const float*)d_in[6];
    const float* ln_b   = (const float*)d_in[7];
    const float* pos    = (const float*)d_in[8];
    float* out = (float*)d_out;
    float* ws  = (float*)d_ws;

    const size_t XA = (size_t)Bsz * Ttok * Cdim;   // 9,793,536 floats
    float* xa      = ws;                 // (B,T,C); reused as out_full for proj
    float* qkv     = ws + XA;            // 3 * XA  (3,B,H,T,hd)
    float* attnout = ws + 4 * XA;        // (B,T,C)
    float* partial = ws + 5 * XA;        // B*16*C
    float* xh      = partial + (size_t)Bsz * 16 * Cdim;  // B*C

    const int M = Bsz * Ttok;  // 12752

    colmean_partial<<<dim3(Bsz, 16), 256, 0, stream>>>(x, partial);
    colmean_reduce<<<Bsz, 256, 0, stream>>>(partial, xh);
    headtok_kernel<<<Bsz * Hn * Hn, 64, 0, stream>>>(xh, htp_w, htp_b, ln_g, ln_b, pos, xa);
    copy_x_to_xa<<<2048, 256, 0, stream>>>((const float4*)x, (float4*)xa);

    gemm_kernel<<<dim3((M + 63) / 64, K3C / 64), 256, 0, stream>>>(
        xa, qkv_w, nullptr, qkv, M, K3C, Cdim, 1);

    attn_kernel<<<Bsz * Hn * 200, 256, 0, stream>>>(
        qkv, qkv + XA, qkv + 2 * XA, attnout);

    gemm_kernel<<<dim3((M + 63) / 64, Cdim / 64), 256, 0, stream>>>(
        attnout, proj_w, proj_b, xa /*out_full*/, M, Cdim, Cdim, 0);

    cls_kernel<<<Bsz, 256, 0, stream>>>(xa, out);
    final_copy<<<2048, 256, 0, stream>>>((const float4*)xa, (float4*)out);
}

// Round 2
// 1104.768 us; speedup vs baseline: 7.8634x; 7.8634x over previous
//
#include <hip/hip_runtime.h>
#include <hip/hip_bf16.h>
#include <math.h>

#define Bsz 16
#define Ntok 785
#define Cdim 768
#define Hn 12
#define HD 64
#define Ttok 797   // Ntok + Hn
#define K3C 2304   // 3*Cdim
#define LN_EPS 1e-5f

typedef __attribute__((ext_vector_type(8))) short short8;
typedef __attribute__((ext_vector_type(4))) float f32x4;

__device__ inline float wave_sum(float v) {
    #pragma unroll
    for (int off = 32; off; off >>= 1) v += __shfl_xor(v, off, 64);
    return v;
}

__device__ inline unsigned short f2bf(float f) {
    unsigned u = __float_as_uint(f);
    u += 0x7fff + ((u >> 16) & 1);
    return (unsigned short)(u >> 16);
}
__device__ inline float bf2f(unsigned short h) { return __uint_as_float(((unsigned)h) << 16); }

// swizzle slot (in ushort units, 8-ushort = 16B granules) for 64-ushort rows
#define SW(row) (((((row) & 7) ^ (((row) >> 3) & 7))) << 3)

// ---------------- column mean over tokens (two-stage, deterministic) -------
__global__ void colmean_partial(const float* __restrict__ x, float* __restrict__ partial) {
    int b = blockIdx.x, ch = blockIdx.y, t = threadIdx.x;
    int n0 = ch * 50, n1 = min(Ntok, n0 + 50);
    float s0 = 0.f, s1 = 0.f, s2 = 0.f;
    for (int n = n0; n < n1; ++n) {
        const float* row = x + ((size_t)b * Ntok + n) * Cdim;
        s0 += row[t]; s1 += row[t + 256]; s2 += row[t + 512];
    }
    float* p = partial + ((size_t)b * 16 + ch) * Cdim;
    p[t] = s0; p[t + 256] = s1; p[t + 512] = s2;
}

__global__ void colmean_reduce(const float* __restrict__ partial, float* __restrict__ xh) {
    int b = blockIdx.x, t = threadIdx.x;
    #pragma unroll
    for (int i = 0; i < 3; ++i) {
        int c = t + i * 256;
        float s = 0.f;
        for (int ch = 0; ch < 16; ++ch) s += partial[((size_t)b * 16 + ch) * Cdim + c];
        xh[(size_t)b * Cdim + c] = s * (1.0f / (float)Ntok);
    }
}

// ------------- head tokens: proj + LayerNorm(hd) + GELU + pos -> xa[N..] ---
__global__ void headtok_kernel(const float* __restrict__ xh, const float* __restrict__ htp_w,
                               const float* __restrict__ htp_b, const float* __restrict__ ln_g,
                               const float* __restrict__ ln_b, const float* __restrict__ pos,
                               float* __restrict__ xa) {
    int blk = blockIdx.x;               // b*H*H + h*H + h2
    int b  = blk / (Hn * Hn);
    int rem = blk % (Hn * Hn);
    int h  = rem / Hn;
    int h2 = rem % Hn;
    int lane = threadIdx.x;             // 0..63 == d within hd
    int c = h2 * HD + lane;

    float acc = htp_b[c];
    const float* xrow = xh + (size_t)b * Cdim + h * HD;
    #pragma unroll 8
    for (int d = 0; d < HD; ++d) acc += xrow[d] * htp_w[(size_t)d * Cdim + c];

    float mu = wave_sum(acc) * (1.0f / 64.0f);
    float diff = acc - mu;
    float var = wave_sum(diff * diff) * (1.0f / 64.0f);
    float y = diff * rsqrtf(var + LN_EPS) * ln_g[lane] + ln_b[lane];
    float g = 0.5f * y * (1.0f + erff(y * 0.70710678118654752f));
    float v = g + pos[(size_t)h * Cdim + c];
    xa[((size_t)b * Ttok + Ntok + h) * Cdim + c] = v;
}

// -------------------- copy x into xa rows [0, N) ---------------------------
__global__ void copy_x_to_xa(const float4* __restrict__ x, float4* __restrict__ xa) {
    const int C4 = Cdim / 4;
    int total = Bsz * Ntok * C4;
    for (int i = blockIdx.x * blockDim.x + threadIdx.x; i < total; i += gridDim.x * blockDim.x) {
        int row = i / C4, c4 = i - row * C4;
        int b = row / Ntok, n = row - b * Ntok;
        xa[((size_t)b * Ttok + n) * C4 + c4] = x[i];
    }
}

// -------------------- fp32 tiled GEMM: Out = A(MxK) @ W(KxN) [+bias] -------
__global__ void gemm_kernel(const float* __restrict__ A, const float* __restrict__ W,
                            const float* __restrict__ bias, float* __restrict__ Out,
                            int M, int Nn, int K, int mode) {
    __shared__ float As[16][68];
    __shared__ float Bs[16][68];
    int tid = threadIdx.x;
    int tx = tid & 15, ty = tid >> 4;
    int mBase = blockIdx.x * 64, nBase = blockIdx.y * 64;

    float acc[4][4];
    #pragma unroll
    for (int i = 0; i < 4; ++i)
        #pragma unroll
        for (int j = 0; j < 4; ++j) acc[i][j] = 0.f;

    int aRow = tid >> 2;
    int aK4  = (tid & 3) * 4;
    int bK   = tid >> 4;
    int bN4  = (tid & 15) * 4;

    for (int k0 = 0; k0 < K; k0 += 16) {
        int gm = mBase + aRow;
        float4 av = make_float4(0.f, 0.f, 0.f, 0.f);
        if (gm < M) av = *reinterpret_cast<const float4*>(&A[(size_t)gm * K + k0 + aK4]);
        As[aK4 + 0][aRow] = av.x; As[aK4 + 1][aRow] = av.y;
        As[aK4 + 2][aRow] = av.z; As[aK4 + 3][aRow] = av.w;
        float4 bv = *reinterpret_cast<const float4*>(&W[(size_t)(k0 + bK) * Nn + nBase + bN4]);
        *reinterpret_cast<float4*>(&Bs[bK][bN4]) = bv;
        __syncthreads();
        #pragma unroll
        for (int kk = 0; kk < 16; ++kk) {
            float4 a4 = *reinterpret_cast<const float4*>(&As[kk][ty * 4]);
            float4 b4 = *reinterpret_cast<const float4*>(&Bs[kk][tx * 4]);
            float a[4] = {a4.x, a4.y, a4.z, a4.w};
            float bb[4] = {b4.x, b4.y, b4.z, b4.w};
            #pragma unroll
            for (int i = 0; i < 4; ++i)
                #pragma unroll
                for (int j = 0; j < 4; ++j) acc[i][j] = fmaf(a[i], bb[j], acc[i][j]);
        }
        __syncthreads();
    }

    #pragma unroll
    for (int i = 0; i < 4; ++i) {
        int gm = mBase + ty * 4 + i;
        if (gm >= M) continue;
        #pragma unroll
        for (int j = 0; j < 4; ++j) {
            int gn = nBase + tx * 4 + j;
            float v = acc[i][j] + (bias ? bias[gn] : 0.f);
            if (mode == 0) {
                Out[(size_t)gm * Nn + gn] = v;
            } else {
                int s = gn / Cdim;
                int hc = gn - s * Cdim;
                int h = hc >> 6, d = hc & 63;
                int b = gm / Ttok, t = gm - b * Ttok;
                Out[(((size_t)(s * Bsz + b) * Hn + h) * Ttok + t) * HD + d] = v;
            }
        }
    }
}

// ==================== MFMA flash attention =================================
// One block per (b*H+h, q-tile of 64 rows); 4 waves, each owns 16 q-rows.
// S = (Qh+Ql)(Kh+Kl)^T via 3 bf16 MFMA passes; P bf16; V split hi/lo.
__global__ __launch_bounds__(256, 2)
void flash_attn_kernel(const float* __restrict__ Qb, const float* __restrict__ Kb,
                       const float* __restrict__ Vb, float* __restrict__ Ob) {
    __shared__ __align__(16) unsigned short KhS[64 * 64];   // [key][dim] swizzled
    __shared__ __align__(16) unsigned short KlS[64 * 64];
    __shared__ __align__(16) unsigned short VhS[64 * 64];   // [dim][key] swizzled (V^T)
    __shared__ __align__(16) unsigned short VlS[64 * 64];
    __shared__ __align__(16) unsigned short PS[4][16 * 64]; // per-wave P [row][key] swizzled

    const int nQT = 13;
    int bh = blockIdx.x / nQT;
    int qt = blockIdx.x % nQT;
    int tid = threadIdx.x;
    int w = tid >> 6, lane = tid & 63;
    int lr = lane & 15, lg = lane >> 4;

    const float* Qg = Qb + (size_t)bh * Ttok * HD;
    const float* Kg = Kb + (size_t)bh * Ttok * HD;
    const float* Vg = Vb + (size_t)bh * Ttok * HD;

    // ---- Q A-fragments (hi/lo), two k-frags covering dims 0..31, 32..63 ----
    short8 qh[2], ql[2];
    {
        int qrow = qt * 64 + w * 16 + lr;
        int crow = min(qrow, Ttok - 1);
        const float* qp = Qg + (size_t)crow * HD + lg * 8;
        #pragma unroll
        for (int kf = 0; kf < 2; ++kf) {
            #pragma unroll
            for (int j = 0; j < 8; ++j) {
                float f = qp[kf * 32 + j];
                unsigned short h = f2bf(f);
                qh[kf][j] = (short)h;
                ql[kf][j] = (short)f2bf(f - bf2f(h));
            }
        }
    }

    f32x4 O[4];
    #pragma unroll
    for (int nt = 0; nt < 4; ++nt) { O[nt][0]=0.f; O[nt][1]=0.f; O[nt][2]=0.f; O[nt][3]=0.f; }
    float mrow[4] = {-1e30f, -1e30f, -1e30f, -1e30f};
    float lrow[4] = {0.f, 0.f, 0.f, 0.f};

    for (int kt = 0; kt < 13; ++kt) {
        __syncthreads();
        // ---------------- stage K, V tile (64 keys) ------------------------
        {
            int key = tid >> 2;
            int dseg = (tid & 3) * 16;
            int gk = kt * 64 + key;
            float kd[16], vd[16];
            if (gk < Ttok) {
                const float* kp = Kg + (size_t)gk * HD + dseg;
                const float* vp = Vg + (size_t)gk * HD + dseg;
                #pragma unroll
                for (int c = 0; c < 4; ++c) {
                    float4 a = *reinterpret_cast<const float4*>(kp + c * 4);
                    float4 bvv = *reinterpret_cast<const float4*>(vp + c * 4);
                    kd[c*4+0]=a.x; kd[c*4+1]=a.y; kd[c*4+2]=a.z; kd[c*4+3]=a.w;
                    vd[c*4+0]=bvv.x; vd[c*4+1]=bvv.y; vd[c*4+2]=bvv.z; vd[c*4+3]=bvv.w;
                }
            } else {
                #pragma unroll
                for (int i = 0; i < 16; ++i) { kd[i] = 0.f; vd[i] = 0.f; }
            }
            int slotK = SW(key);
            #pragma unroll
            for (int c = 0; c < 2; ++c) {
                short8 h8, l8;
                #pragma unroll
                for (int j = 0; j < 8; ++j) {
                    float f = kd[c * 8 + j];
                    unsigned short h = f2bf(f);
                    h8[j] = (short)h;
                    l8[j] = (short)f2bf(f - bf2f(h));
                }
                int idx = (key * 64 + dseg + c * 8) ^ slotK;
                *reinterpret_cast<short8*>(&KhS[idx]) = h8;
                *reinterpret_cast<short8*>(&KlS[idx]) = l8;
            }
            #pragma unroll
            for (int i = 0; i < 16; ++i) {
                int dim = dseg + i;
                float f = vd[i];
                unsigned short h = f2bf(f);
                int idx = (dim * 64 + key) ^ SW(dim);
                VhS[idx] = h;
                VlS[idx] = f2bf(f - bf2f(h));
            }
        }
        __syncthreads();

        // ---------------- S = Q K^T (3-pass hi/lo split) --------------------
        f32x4 s[4];
        #pragma unroll
        for (int nt = 0; nt < 4; ++nt) { s[nt][0]=0.f; s[nt][1]=0.f; s[nt][2]=0.f; s[nt][3]=0.f; }
        #pragma unroll
        for (int kf = 0; kf < 2; ++kf) {
            #pragma unroll
            for (int nt = 0; nt < 4; ++nt) {
                int key = nt * 16 + lr;
                int d0 = kf * 32 + lg * 8;
                int idx = (key * 64 + d0) ^ SW(key);
                short8 bh8 = *reinterpret_cast<const short8*>(&KhS[idx]);
                short8 bl8 = *reinterpret_cast<const short8*>(&KlS[idx]);
                s[nt] = __builtin_amdgcn_mfma_f32_16x16x32_bf16(qh[kf], bh8, s[nt], 0, 0, 0);
                s[nt] = __builtin_amdgcn_mfma_f32_16x16x32_bf16(ql[kf], bh8, s[nt], 0, 0, 0);
                s[nt] = __builtin_amdgcn_mfma_f32_16x16x32_bf16(qh[kf], bl8, s[nt], 0, 0, 0);
            }
        }
        // mask invalid keys + scale
        int kbase = kt * 64;
        #pragma unroll
        for (int nt = 0; nt < 4; ++nt) {
            bool invalid = (kbase + nt * 16 + lr) >= Ttok;
            #pragma unroll
            for (int r = 0; r < 4; ++r) {
                float sv = s[nt][r] * 0.125f;
                s[nt][r] = invalid ? -1e30f : sv;
            }
        }
        // row max (across 4 n-frags in-lane, then 16 lanes of the row group)
        float rmax[4];
        #pragma unroll
        for (int r = 0; r < 4; ++r)
            rmax[r] = fmaxf(fmaxf(s[0][r], s[1][r]), fmaxf(s[2][r], s[3][r]));
        #pragma unroll
        for (int off = 1; off < 16; off <<= 1)
            #pragma unroll
            for (int r = 0; r < 4; ++r)
                rmax[r] = fmaxf(rmax[r], __shfl_xor(rmax[r], off, 64));
        float corr[4];
        #pragma unroll
        for (int r = 0; r < 4; ++r) {
            float mn = fmaxf(mrow[r], rmax[r]);
            corr[r] = __expf(mrow[r] - mn);
            mrow[r] = mn;
        }
        // p = exp(s - m), row sums
        float psum[4] = {0.f, 0.f, 0.f, 0.f};
        #pragma unroll
        for (int nt = 0; nt < 4; ++nt)
            #pragma unroll
            for (int r = 0; r < 4; ++r) {
                float p = __expf(s[nt][r] - mrow[r]);
                s[nt][r] = p;
                psum[r] += p;
            }
        #pragma unroll
        for (int off = 1; off < 16; off <<= 1)
            #pragma unroll
            for (int r = 0; r < 4; ++r)
                psum[r] += __shfl_xor(psum[r], off, 64);
        #pragma unroll
        for (int r = 0; r < 4; ++r) lrow[r] = lrow[r] * corr[r] + psum[r];
        // rescale O
        #pragma unroll
        for (int nt = 0; nt < 4; ++nt)
            #pragma unroll
            for (int r = 0; r < 4; ++r) O[nt][r] *= corr[r];
        // P (D-layout) -> LDS bf16 (swizzled)
        unsigned short* Pw = &PS[w][0];
        #pragma unroll
        for (int nt = 0; nt < 4; ++nt)
            #pragma unroll
            for (int r = 0; r < 4; ++r) {
                int row = lg * 4 + r;
                int col = nt * 16 + lr;
                Pw[(row * 64 + col) ^ SW(row)] = f2bf(s[nt][r]);
            }
        // P A-frags
        short8 pa[2];
        #pragma unroll
        for (int kf = 0; kf < 2; ++kf)
            pa[kf] = *reinterpret_cast<const short8*>(&Pw[(lr * 64 + kf * 32 + lg * 8) ^ SW(lr)]);
        // O += P V  (V split hi/lo)
        #pragma unroll
        for (int kf = 0; kf < 2; ++kf) {
            #pragma unroll
            for (int nt = 0; nt < 4; ++nt) {
                int dim = nt * 16 + lr;
                int k0 = kf * 32 + lg * 8;
                int idx = (dim * 64 + k0) ^ SW(dim);
                short8 vh8 = *reinterpret_cast<const short8*>(&VhS[idx]);
                short8 vl8 = *reinterpret_cast<const short8*>(&VlS[idx]);
                O[nt] = __builtin_amdgcn_mfma_f32_16x16x32_bf16(pa[kf], vh8, O[nt], 0, 0, 0);
                O[nt] = __builtin_amdgcn_mfma_f32_16x16x32_bf16(pa[kf], vl8, O[nt], 0, 0, 0);
            }
        }
    }

    // ---------------- epilogue: O /= l, store ------------------------------
    int b = bh / Hn, h = bh % Hn;
    #pragma unroll
    for (int r = 0; r < 4; ++r) {
        int qrow = qt * 64 + w * 16 + lg * 4 + r;
        if (qrow >= Ttok) continue;
        float inv = 1.0f / lrow[r];
        #pragma unroll
        for (int nt = 0; nt < 4; ++nt)
            Ob[((size_t)b * Ttok + qrow) * Cdim + h * HD + nt * 16 + lr] = O[nt][r] * inv;
    }
}

// -------------------- epilogue: cls row + copy rows 1..N-1 -----------------
__global__ void cls_kernel(const float* __restrict__ out_full, float* __restrict__ out) {
    int b = blockIdx.x, t = threadIdx.x;
    #pragma unroll
    for (int i = 0; i < 3; ++i) {
        int c = t + i * 256;
        float s = out_full[((size_t)b * Ttok) * Cdim + c];
        float hs = 0.f;
        #pragma unroll
        for (int h = 0; h < Hn; ++h)
            hs += out_full[((size_t)b * Ttok + Ntok + h) * Cdim + c];
        out[((size_t)b * Ntok) * Cdim + c] = s + hs * (1.0f / (float)Hn);
    }
}

__global__ void final_copy(const float4* __restrict__ out_full, float4* __restrict__ out) {
    const int C4 = Cdim / 4;
    int total = Bsz * (Ntok - 1) * C4;
    for (int i = blockIdx.x * blockDim.x + threadIdx.x; i < total; i += gridDim.x * blockDim.x) {
        int row = i / C4, c4 = i - row * C4;
        int b = row / (Ntok - 1), n = 1 + row - b * (Ntok - 1);
        out[((size_t)b * Ntok + n) * C4 + c4] = out_full[((size_t)b * Ttok + n) * C4 + c4];
    }
}

extern "C" void kernel_launch(void* const* d_in, const int* in_sizes, int n_in,
                              void* d_out, int out_size, void* d_ws, size_t ws_size,
                              hipStream_t stream) {
    const float* x      = (const float*)d_in[0];
    const float* qkv_w  = (const float*)d_in[1];
    const float* proj_w = (const float*)d_in[2];
    const float* proj_b = (const float*)d_in[3];
    const float* htp_w  = (const float*)d_in[4];
    const float* htp_b  = (const float*)d_in[5];
    const float* ln_g   = (const float*)d_in[6];
    const float* ln_b   = (const float*)d_in[7];
    const float* pos    = (const float*)d_in[8];
    float* out = (float*)d_out;
    float* ws  = (float*)d_ws;

    const size_t XA = (size_t)Bsz * Ttok * Cdim;
    float* xa      = ws;
    float* qkv     = ws + XA;
    float* attnout = ws + 4 * XA;
    float* partial = ws + 5 * XA;
    float* xh      = partial + (size_t)Bsz * 16 * Cdim;

    const int M = Bsz * Ttok;

    colmean_partial<<<dim3(Bsz, 16), 256, 0, stream>>>(x, partial);
    colmean_reduce<<<Bsz, 256, 0, stream>>>(partial, xh);
    headtok_kernel<<<Bsz * Hn * Hn, 64, 0, stream>>>(xh, htp_w, htp_b, ln_g, ln_b, pos, xa);
    copy_x_to_xa<<<2048, 256, 0, stream>>>((const float4*)x, (float4*)xa);

    gemm_kernel<<<dim3((M + 63) / 64, K3C / 64), 256, 0, stream>>>(
        xa, qkv_w, nullptr, qkv, M, K3C, Cdim, 1);

    flash_attn_kernel<<<Bsz * Hn * 13, 256, 0, stream>>>(
        qkv, qkv + XA, qkv + 2 * XA, attnout);

    gemm_kernel<<<dim3((M + 63) / 64, Cdim / 64), 256, 0, stream>>>(
        attnout, proj_w, proj_b, xa, M, Cdim, Cdim, 0);

    cls_kernel<<<Bsz, 256, 0, stream>>>(xa, out);
    final_copy<<<2048, 256, 0, stream>>>((const float4*)xa, (float4*)out);
}

// Round 3
// 808.039 us; speedup vs baseline: 10.7510x; 1.3672x over previous
//
#include <hip/hip_runtime.h>
#include <hip/hip_bf16.h>
#include <math.h>

#define Bsz 16
#define Ntok 785
#define Cdim 768
#define Hn 12
#define HD 64
#define Ttok 797   // Ntok + Hn
#define Kdim 768
#define K3C 2304   // 3*Cdim
#define LN_EPS 1e-5f
#define Mrows (Bsz * Ttok)            // 12752

typedef __attribute__((ext_vector_type(8))) short short8;
typedef __attribute__((ext_vector_type(4))) float f32x4;
typedef unsigned short ushort_t;

__device__ inline float wave_sum(float v) {
    #pragma unroll
    for (int off = 32; off; off >>= 1) v += __shfl_xor(v, off, 64);
    return v;
}

__device__ inline ushort_t f2bf(float f) {
    unsigned u = __float_as_uint(f);
    u += 0x7fff + ((u >> 16) & 1);
    return (ushort_t)(u >> 16);
}
__device__ inline float bf2f(ushort_t h) { return __uint_as_float(((unsigned)h) << 16); }

// swizzle slot (in ushort units, 8-ushort = 16B granules) for 64-ushort rows
#define SW(row) (((((row) & 7) ^ (((row) >> 3) & 7))) << 3)

// ---------------- column mean over tokens (two-stage, deterministic) -------
__global__ void colmean_partial(const float* __restrict__ x, float* __restrict__ partial) {
    int b = blockIdx.x, ch = blockIdx.y, t = threadIdx.x;
    int n0 = ch * 50, n1 = min(Ntok, n0 + 50);
    float s0 = 0.f, s1 = 0.f, s2 = 0.f;
    for (int n = n0; n < n1; ++n) {
        const float* row = x + ((size_t)b * Ntok + n) * Cdim;
        s0 += row[t]; s1 += row[t + 256]; s2 += row[t + 512];
    }
    float* p = partial + ((size_t)b * 16 + ch) * Cdim;
    p[t] = s0; p[t + 256] = s1; p[t + 512] = s2;
}

__global__ void colmean_reduce(const float* __restrict__ partial, float* __restrict__ xh) {
    int b = blockIdx.x, t = threadIdx.x;
    #pragma unroll
    for (int i = 0; i < 3; ++i) {
        int c = t + i * 256;
        float s = 0.f;
        for (int ch = 0; ch < 16; ++ch) s += partial[((size_t)b * 16 + ch) * Cdim + c];
        xh[(size_t)b * Cdim + c] = s * (1.0f / (float)Ntok);
    }
}

// ------------- head tokens: proj + LN + GELU + pos -> xa rows [N..T) -------
__global__ void headtok_kernel(const float* __restrict__ xh, const float* __restrict__ htp_w,
                               const float* __restrict__ htp_b, const float* __restrict__ ln_g,
                               const float* __restrict__ ln_b, const float* __restrict__ pos,
                               ushort_t* __restrict__ xah, ushort_t* __restrict__ xal) {
    int blk = blockIdx.x;
    int b  = blk / (Hn * Hn);
    int rem = blk % (Hn * Hn);
    int h  = rem / Hn;
    int h2 = rem % Hn;
    int lane = threadIdx.x;
    int c = h2 * HD + lane;

    float acc = htp_b[c];
    const float* xrow = xh + (size_t)b * Cdim + h * HD;
    #pragma unroll 8
    for (int d = 0; d < HD; ++d) acc += xrow[d] * htp_w[(size_t)d * Cdim + c];

    float mu = wave_sum(acc) * (1.0f / 64.0f);
    float diff = acc - mu;
    float var = wave_sum(diff * diff) * (1.0f / 64.0f);
    float y = diff * rsqrtf(var + LN_EPS) * ln_g[lane] + ln_b[lane];
    float g = 0.5f * y * (1.0f + erff(y * 0.70710678118654752f));
    float v = g + pos[(size_t)h * Cdim + c];
    size_t o = ((size_t)b * Ttok + Ntok + h) * Cdim + c;
    ushort_t hh = f2bf(v);
    xah[o] = hh;
    xal[o] = f2bf(v - bf2f(hh));
}

// -------------------- x -> xa rows [0,N), split hi/lo bf16 -----------------
__global__ void copy_x_split(const float4* __restrict__ x, ushort_t* __restrict__ xah,
                             ushort_t* __restrict__ xal) {
    const int C4 = Cdim / 4;
    int total = Bsz * Ntok * C4;
    for (int i = blockIdx.x * blockDim.x + threadIdx.x; i < total; i += gridDim.x * blockDim.x) {
        int row = i / C4, c4 = i - row * C4;
        int b = row / Ntok, n = row - b * Ntok;
        float4 v = x[i];
        float f[4] = {v.x, v.y, v.z, v.w};
        ushort_t hs[4], ls[4];
        #pragma unroll
        for (int j = 0; j < 4; ++j) {
            hs[j] = f2bf(f[j]);
            ls[j] = f2bf(f[j] - bf2f(hs[j]));
        }
        size_t o = ((size_t)b * Ttok + n) * Cdim + c4 * 4;
        *reinterpret_cast<ushort4*>(&xah[o]) = make_ushort4(hs[0], hs[1], hs[2], hs[3]);
        *reinterpret_cast<ushort4*>(&xal[o]) = make_ushort4(ls[0], ls[1], ls[2], ls[3]);
    }
}

// ------------- W[K][N] -> W^T hi/lo bf16 [N][K] (LDS tile transpose) -------
__global__ void convert_wT(const float* __restrict__ W, ushort_t* __restrict__ WhT,
                           ushort_t* __restrict__ WlT, int K, int N) {
    __shared__ float tile[32][33];
    int nt = blockIdx.x * 32, kt = blockIdx.y * 32;
    int tx = threadIdx.x & 31, ty = threadIdx.x >> 5;  // ty 0..7
    #pragma unroll
    for (int r = 0; r < 32; r += 8)
        tile[ty + r][tx] = W[(size_t)(kt + ty + r) * N + nt + tx];
    __syncthreads();
    #pragma unroll
    for (int r = 0; r < 32; r += 8) {
        int n = nt + ty + r, k = kt + tx;
        float f = tile[tx][ty + r];
        ushort_t hh = f2bf(f);
        WhT[(size_t)n * K + k] = hh;
        WlT[(size_t)n * K + k] = f2bf(f - bf2f(hh));
    }
}

// ==================== MFMA split-bf16 GEMM =================================
// C[M][N] = A[M][K] * W[K][N] via A=Ah+Al, W=Wh+Wl (bf16), 3-pass MFMA.
// A given row-major hi/lo; W given TRANSPOSED hi/lo ([N][K]).
// 128x128 tile, 4 waves, BK=32, global_load_lds staging, k-grouped LDS.
// mode 0: fp32 out [M][N] (+bias). mode 1: scatter hi/lo bf16 to (3,B,H,T,hd).
__global__ __launch_bounds__(256, 2)
void mfma_gemm(const ushort_t* __restrict__ Ah, const ushort_t* __restrict__ Al,
               const ushort_t* __restrict__ Wh, const ushort_t* __restrict__ Wl,
               const float* __restrict__ bias, int M, int Nn, int mode,
               float* __restrict__ outF, ushort_t* __restrict__ outH,
               ushort_t* __restrict__ outL) {
    // per tile: [4 kb][128 row][8 ushorts] = 8KB; 4 tiles (Ah,Al,Wh,Wl); x2 dbuf
    __shared__ __align__(16) ushort_t smem[2][4][4096];
    const int tid = threadIdx.x;
    const int w = tid >> 6, lane = tid & 63;
    const int lr = lane & 15, lg = lane >> 4;
    const int wr = w >> 1, wc = w & 1;
    const int mBase = blockIdx.x * 128, nBase = blockIdx.y * 128;

    const ushort_t* src = (w == 0) ? Ah : (w == 1) ? Al : (w == 2) ? Wh : Wl;
    const int rowBase = (w < 2) ? mBase : nBase;
    const int rowMax  = (w < 2) ? (M - 1) : (Nn - 1);

    f32x4 acc[4][4];
    #pragma unroll
    for (int mi = 0; mi < 4; ++mi)
        #pragma unroll
        for (int ni = 0; ni < 4; ++ni) {
            acc[mi][ni][0] = 0.f; acc[mi][ni][1] = 0.f;
            acc[mi][ni][2] = 0.f; acc[mi][ni][3] = 0.f;
        }

    auto stage = [&](int buf, int k0) {
        ushort_t* dst = &smem[buf][w][0];
        #pragma unroll
        for (int kb = 0; kb < 4; ++kb) {
            #pragma unroll
            for (int half = 0; half < 2; ++half) {
                int row = min(rowBase + half * 64 + lane, rowMax);
                const ushort_t* g = src + (size_t)row * Kdim + k0 + kb * 8;
                ushort_t* l = dst + kb * 1024 + half * 512;   // + lane*8 by HW
                __builtin_amdgcn_global_load_lds(
                    (const __attribute__((address_space(1))) void*)g,
                    (__attribute__((address_space(3))) void*)l, 16, 0, 0);
            }
        }
    };

    stage(0, 0);
    int cur = 0;
    const int NT = Kdim / 32;  // 24
    for (int t = 0; t < NT; ++t) {
        __syncthreads();
        if (t + 1 < NT) stage(cur ^ 1, (t + 1) * 32);
        const ushort_t* AhS = &smem[cur][0][0];
        const ushort_t* AlS = &smem[cur][1][0];
        const ushort_t* WhS = &smem[cur][2][0];
        const ushort_t* WlS = &smem[cur][3][0];
        short8 a[2][4], b[2][4];
        #pragma unroll
        for (int mi = 0; mi < 4; ++mi) {
            int idx = lg * 1024 + (wr * 64 + mi * 16 + lr) * 8;
            a[0][mi] = *reinterpret_cast<const short8*>(&AhS[idx]);
            a[1][mi] = *reinterpret_cast<const short8*>(&AlS[idx]);
        }
        #pragma unroll
        for (int ni = 0; ni < 4; ++ni) {
            int idx = lg * 1024 + (wc * 64 + ni * 16 + lr) * 8;
            b[0][ni] = *reinterpret_cast<const short8*>(&WhS[idx]);
            b[1][ni] = *reinterpret_cast<const short8*>(&WlS[idx]);
        }
        #pragma unroll
        for (int mi = 0; mi < 4; ++mi)
            #pragma unroll
            for (int ni = 0; ni < 4; ++ni) {
                acc[mi][ni] = __builtin_amdgcn_mfma_f32_16x16x32_bf16(a[0][mi], b[0][ni], acc[mi][ni], 0, 0, 0);
                acc[mi][ni] = __builtin_amdgcn_mfma_f32_16x16x32_bf16(a[1][mi], b[0][ni], acc[mi][ni], 0, 0, 0);
                acc[mi][ni] = __builtin_amdgcn_mfma_f32_16x16x32_bf16(a[0][mi], b[1][ni], acc[mi][ni], 0, 0, 0);
            }
        cur ^= 1;
    }

    #pragma unroll
    for (int ni = 0; ni < 4; ++ni) {
        int gn = nBase + wc * 64 + ni * 16 + lr;
        if (mode == 0) {
            float bv = bias ? bias[gn] : 0.f;
            #pragma unroll
            for (int mi = 0; mi < 4; ++mi)
                #pragma unroll
                for (int r = 0; r < 4; ++r) {
                    int gm = mBase + wr * 64 + mi * 16 + lg * 4 + r;
                    if (gm < M) outF[(size_t)gm * Nn + gn] = acc[mi][ni][r] + bv;
                }
        } else {
            int s = gn / Cdim;
            int hc = gn - s * Cdim;
            int h = hc >> 6, d = hc & 63;
            #pragma unroll
            for (int mi = 0; mi < 4; ++mi)
                #pragma unroll
                for (int r = 0; r < 4; ++r) {
                    int gm = mBase + wr * 64 + mi * 16 + lg * 4 + r;
                    if (gm < M) {
                        int bb = gm / Ttok, tt = gm - bb * Ttok;
                        size_t o = (((size_t)(s * Bsz + bb) * Hn + h) * Ttok + tt) * HD + d;
                        float v = acc[mi][ni][r];
                        ushort_t hh = f2bf(v);
                        outH[o] = hh;
                        outL[o] = f2bf(v - bf2f(hh));
                    }
                }
        }
    }
}

// ==================== MFMA flash attention (bf16 hi/lo I/O) ================
__global__ __launch_bounds__(256, 2)
void flash_attn_kernel(const ushort_t* __restrict__ Qh, const ushort_t* __restrict__ Ql,
                       const ushort_t* __restrict__ Kh, const ushort_t* __restrict__ Kl,
                       const ushort_t* __restrict__ Vh, const ushort_t* __restrict__ Vl,
                       ushort_t* __restrict__ aoh, ushort_t* __restrict__ aol) {
    __shared__ __align__(16) ushort_t KhS[64 * 64];
    __shared__ __align__(16) ushort_t KlS[64 * 64];
    __shared__ __align__(16) ushort_t VhS[64 * 64];   // transposed [dim][key]
    __shared__ __align__(16) ushort_t VlS[64 * 64];
    __shared__ __align__(16) ushort_t PS[4][16 * 64];

    const int nQT = 13;
    int bh = blockIdx.x / nQT;
    int qt = blockIdx.x % nQT;
    int tid = threadIdx.x;
    int w = tid >> 6, lane = tid & 63;
    int lr = lane & 15, lg = lane >> 4;
    size_t base = (size_t)bh * Ttok * HD;

    short8 qfh[2], qfl[2];
    {
        int qrow = qt * 64 + w * 16 + lr;
        int crow = min(qrow, Ttok - 1);
        #pragma unroll
        for (int kf = 0; kf < 2; ++kf) {
            qfh[kf] = *reinterpret_cast<const short8*>(Qh + base + (size_t)crow * HD + kf * 32 + lg * 8);
            qfl[kf] = *reinterpret_cast<const short8*>(Ql + base + (size_t)crow * HD + kf * 32 + lg * 8);
        }
    }

    f32x4 O[4];
    #pragma unroll
    for (int nt = 0; nt < 4; ++nt) { O[nt][0]=0.f; O[nt][1]=0.f; O[nt][2]=0.f; O[nt][3]=0.f; }
    float mrow[4] = {-1e30f, -1e30f, -1e30f, -1e30f};
    float lrow[4] = {0.f, 0.f, 0.f, 0.f};

    for (int kt = 0; kt < 13; ++kt) {
        __syncthreads();
        {
            int key = tid >> 2;
            int dseg = (tid & 3) * 16;
            int gk = kt * 64 + key;
            int slotK = SW(key);
            if (gk < Ttok) {
                const ushort_t* kph = Kh + base + (size_t)gk * HD + dseg;
                const ushort_t* kpl = Kl + base + (size_t)gk * HD + dseg;
                const ushort_t* vph = Vh + base + (size_t)gk * HD + dseg;
                const ushort_t* vpl = Vl + base + (size_t)gk * HD + dseg;
                #pragma unroll
                for (int c = 0; c < 2; ++c) {
                    *reinterpret_cast<short8*>(&KhS[(key * 64 + dseg + c * 8) ^ slotK]) =
                        *reinterpret_cast<const short8*>(kph + c * 8);
                    *reinterpret_cast<short8*>(&KlS[(key * 64 + dseg + c * 8) ^ slotK]) =
                        *reinterpret_cast<const short8*>(kpl + c * 8);
                }
                short8 vh8[2], vl8[2];
                #pragma unroll
                for (int c = 0; c < 2; ++c) {
                    vh8[c] = *reinterpret_cast<const short8*>(vph + c * 8);
                    vl8[c] = *reinterpret_cast<const short8*>(vpl + c * 8);
                }
                #pragma unroll
                for (int c = 0; c < 2; ++c)
                    #pragma unroll
                    for (int j = 0; j < 8; ++j) {
                        int dim = dseg + c * 8 + j;
                        VhS[(dim * 64 + key) ^ SW(dim)] = (ushort_t)vh8[c][j];
                        VlS[(dim * 64 + key) ^ SW(dim)] = (ushort_t)vl8[c][j];
                    }
            } else {
                short8 z = {0, 0, 0, 0, 0, 0, 0, 0};
                #pragma unroll
                for (int c = 0; c < 2; ++c) {
                    *reinterpret_cast<short8*>(&KhS[(key * 64 + dseg + c * 8) ^ slotK]) = z;
                    *reinterpret_cast<short8*>(&KlS[(key * 64 + dseg + c * 8) ^ slotK]) = z;
                }
                #pragma unroll
                for (int i = 0; i < 16; ++i) {
                    int dim = dseg + i;
                    VhS[(dim * 64 + key) ^ SW(dim)] = 0;
                    VlS[(dim * 64 + key) ^ SW(dim)] = 0;
                }
            }
        }
        __syncthreads();

        f32x4 s[4];
        #pragma unroll
        for (int nt = 0; nt < 4; ++nt) { s[nt][0]=0.f; s[nt][1]=0.f; s[nt][2]=0.f; s[nt][3]=0.f; }
        #pragma unroll
        for (int kf = 0; kf < 2; ++kf) {
            #pragma unroll
            for (int nt = 0; nt < 4; ++nt) {
                int key = nt * 16 + lr;
                int d0 = kf * 32 + lg * 8;
                int idx = (key * 64 + d0) ^ SW(key);
                short8 bh8 = *reinterpret_cast<const short8*>(&KhS[idx]);
                short8 bl8 = *reinterpret_cast<const short8*>(&KlS[idx]);
                s[nt] = __builtin_amdgcn_mfma_f32_16x16x32_bf16(qfh[kf], bh8, s[nt], 0, 0, 0);
                s[nt] = __builtin_amdgcn_mfma_f32_16x16x32_bf16(qfl[kf], bh8, s[nt], 0, 0, 0);
                s[nt] = __builtin_amdgcn_mfma_f32_16x16x32_bf16(qfh[kf], bl8, s[nt], 0, 0, 0);
            }
        }
        int kbase = kt * 64;
        #pragma unroll
        for (int nt = 0; nt < 4; ++nt) {
            bool invalid = (kbase + nt * 16 + lr) >= Ttok;
            #pragma unroll
            for (int r = 0; r < 4; ++r) {
                float sv = s[nt][r] * 0.125f;
                s[nt][r] = invalid ? -1e30f : sv;
            }
        }
        float rmax[4];
        #pragma unroll
        for (int r = 0; r < 4; ++r)
            rmax[r] = fmaxf(fmaxf(s[0][r], s[1][r]), fmaxf(s[2][r], s[3][r]));
        #pragma unroll
        for (int off = 1; off < 16; off <<= 1)
            #pragma unroll
            for (int r = 0; r < 4; ++r)
                rmax[r] = fmaxf(rmax[r], __shfl_xor(rmax[r], off, 64));
        float corr[4];
        #pragma unroll
        for (int r = 0; r < 4; ++r) {
            float mn = fmaxf(mrow[r], rmax[r]);
            corr[r] = __expf(mrow[r] - mn);
            mrow[r] = mn;
        }
        float psum[4] = {0.f, 0.f, 0.f, 0.f};
        #pragma unroll
        for (int nt = 0; nt < 4; ++nt)
            #pragma unroll
            for (int r = 0; r < 4; ++r) {
                float p = __expf(s[nt][r] - mrow[r]);
                s[nt][r] = p;
                psum[r] += p;
            }
        #pragma unroll
        for (int off = 1; off < 16; off <<= 1)
            #pragma unroll
            for (int r = 0; r < 4; ++r)
                psum[r] += __shfl_xor(psum[r], off, 64);
        #pragma unroll
        for (int r = 0; r < 4; ++r) lrow[r] = lrow[r] * corr[r] + psum[r];
        #pragma unroll
        for (int nt = 0; nt < 4; ++nt)
            #pragma unroll
            for (int r = 0; r < 4; ++r) O[nt][r] *= corr[r];
        ushort_t* Pw = &PS[w][0];
        #pragma unroll
        for (int nt = 0; nt < 4; ++nt)
            #pragma unroll
            for (int r = 0; r < 4; ++r) {
                int row = lg * 4 + r;
                int col = nt * 16 + lr;
                Pw[(row * 64 + col) ^ SW(row)] = f2bf(s[nt][r]);
            }
        short8 pa[2];
        #pragma unroll
        for (int kf = 0; kf < 2; ++kf)
            pa[kf] = *reinterpret_cast<const short8*>(&Pw[(lr * 64 + kf * 32 + lg * 8) ^ SW(lr)]);
        #pragma unroll
        for (int kf = 0; kf < 2; ++kf) {
            #pragma unroll
            for (int nt = 0; nt < 4; ++nt) {
                int dim = nt * 16 + lr;
                int k0 = kf * 32 + lg * 8;
                int idx = (dim * 64 + k0) ^ SW(dim);
                short8 vh8 = *reinterpret_cast<const short8*>(&VhS[idx]);
                short8 vl8 = *reinterpret_cast<const short8*>(&VlS[idx]);
                O[nt] = __builtin_amdgcn_mfma_f32_16x16x32_bf16(pa[kf], vh8, O[nt], 0, 0, 0);
                O[nt] = __builtin_amdgcn_mfma_f32_16x16x32_bf16(pa[kf], vl8, O[nt], 0, 0, 0);
            }
        }
    }

    int b = bh / Hn, h = bh % Hn;
    #pragma unroll
    for (int r = 0; r < 4; ++r) {
        int qrow = qt * 64 + w * 16 + lg * 4 + r;
        if (qrow >= Ttok) continue;
        float inv = 1.0f / lrow[r];
        #pragma unroll
        for (int nt = 0; nt < 4; ++nt) {
            float v = O[nt][r] * inv;
            size_t o = ((size_t)b * Ttok + qrow) * Cdim + h * HD + nt * 16 + lr;
            ushort_t hh = f2bf(v);
            aoh[o] = hh;
            aol[o] = f2bf(v - bf2f(hh));
        }
    }
}

// -------------------- epilogue: cls row + copy rows 1..N-1 -----------------
__global__ void cls_kernel(const float* __restrict__ out_full, float* __restrict__ out) {
    int b = blockIdx.x, t = threadIdx.x;
    #pragma unroll
    for (int i = 0; i < 3; ++i) {
        int c = t + i * 256;
        float s = out_full[((size_t)b * Ttok) * Cdim + c];
        float hs = 0.f;
        #pragma unroll
        for (int h = 0; h < Hn; ++h)
            hs += out_full[((size_t)b * Ttok + Ntok + h) * Cdim + c];
        out[((size_t)b * Ntok) * Cdim + c] = s + hs * (1.0f / (float)Hn);
    }
}

__global__ void final_copy(const float4* __restrict__ out_full, float4* __restrict__ out) {
    const int C4 = Cdim / 4;
    int total = Bsz * (Ntok - 1) * C4;
    for (int i = blockIdx.x * blockDim.x + threadIdx.x; i < total; i += gridDim.x * blockDim.x) {
        int row = i / C4, c4 = i - row * C4;
        int b = row / (Ntok - 1), n = 1 + row - b * (Ntok - 1);
        out[((size_t)b * Ntok + n) * C4 + c4] = out_full[((size_t)b * Ttok + n) * C4 + c4];
    }
}

extern "C" void kernel_launch(void* const* d_in, const int* in_sizes, int n_in,
                              void* d_out, int out_size, void* d_ws, size_t ws_size,
                              hipStream_t stream) {
    const float* x      = (const float*)d_in[0];
    const float* qkv_w  = (const float*)d_in[1];
    const float* proj_w = (const float*)d_in[2];
    const float* proj_b = (const float*)d_in[3];
    const float* htp_w  = (const float*)d_in[4];
    const float* htp_b  = (const float*)d_in[5];
    const float* ln_g   = (const float*)d_in[6];
    const float* ln_b   = (const float*)d_in[7];
    const float* pos    = (const float*)d_in[8];
    float* out = (float*)d_out;

    const size_t MC = (size_t)Mrows * Cdim;        // 9,793,536
    const size_t WQ = (size_t)K3C * Kdim;          // 1,769,472
    const size_t WP = (size_t)Cdim * Kdim;         // 589,824

    ushort_t* qkvh = (ushort_t*)d_ws;              // 3*MC
    ushort_t* qkvl = qkvh + 3 * MC;                // 3*MC
    ushort_t* xah  = qkvl + 3 * MC;                // MC   (later reused as aoh)
    ushort_t* xal  = xah + MC;                     // MC   (later reused as aol)
    ushort_t* wqh  = xal + MC;
    ushort_t* wql  = wqh + WQ;
    ushort_t* wph  = wql + WQ;
    ushort_t* wpl  = wph + WP;
    float* partial = (float*)(wpl + WP);           // B*16*C
    float* xh      = partial + (size_t)Bsz * 16 * Cdim;
    float* out_full = (float*)qkvh;                // reuse qkv hi region after attn

    colmean_partial<<<dim3(Bsz, 16), 256, 0, stream>>>(x, partial);
    colmean_reduce<<<Bsz, 256, 0, stream>>>(partial, xh);
    headtok_kernel<<<Bsz * Hn * Hn, 64, 0, stream>>>(xh, htp_w, htp_b, ln_g, ln_b, pos, xah, xal);
    copy_x_split<<<2048, 256, 0, stream>>>((const float4*)x, xah, xal);
    convert_wT<<<dim3(K3C / 32, Kdim / 32), 256, 0, stream>>>(qkv_w, wqh, wql, Kdim, K3C);
    convert_wT<<<dim3(Cdim / 32, Kdim / 32), 256, 0, stream>>>(proj_w, wph, wpl, Kdim, Cdim);

    mfma_gemm<<<dim3((Mrows + 127) / 128, K3C / 128), 256, 0, stream>>>(
        xah, xal, wqh, wql, nullptr, Mrows, K3C, 1, nullptr, qkvh, qkvl);

    flash_attn_kernel<<<Bsz * Hn * 13, 256, 0, stream>>>(
        qkvh, qkvl, qkvh + MC, qkvl + MC, qkvh + 2 * MC, qkvl + 2 * MC, xah, xal);

    mfma_gemm<<<dim3((Mrows + 127) / 128, Cdim / 128), 256, 0, stream>>>(
        xah, xal, wph, wpl, proj_b, Mrows, Cdim, 0, out_full, nullptr, nullptr);

    cls_kernel<<<Bsz, 256, 0, stream>>>(out_full, out);
    final_copy<<<2048, 256, 0, stream>>>((const float4*)out_full, (float4*)out);
}

// Round 4
// 359.249 us; speedup vs baseline: 24.1815x; 2.2492x over previous
//
#include <hip/hip_runtime.h>
#include <hip/hip_bf16.h>
#include <math.h>

#define Bsz 16
#define Ntok 785
#define Cdim 768
#define Hn 12
#define HD 64
#define Ttok 797   // Ntok + Hn
#define Kdim 768
#define K3C 2304   // 3*Cdim
#define LN_EPS 1e-5f
#define Mrows (Bsz * Ttok)            // 12752

typedef _Float16 f16;
typedef __attribute__((ext_vector_type(8))) _Float16 half8;
typedef __attribute__((ext_vector_type(4))) float f32x4;

__device__ inline float wave_sum(float v) {
    #pragma unroll
    for (int off = 32; off; off >>= 1) v += __shfl_xor(v, off, 64);
    return v;
}

// swizzle slot (in f16 units, 8-f16 = 16B granules) for 64-f16 rows
#define SW(row) (((((row) & 7) ^ (((row) >> 3) & 7))) << 3)

// ------- fused: column-sum partials over tokens + x -> fp16 xa rows --------
__global__ void prep_x(const float* __restrict__ x, f16* __restrict__ xa,
                       float* __restrict__ partial) {
    int b = blockIdx.x, ch = blockIdx.y, t = threadIdx.x;
    int n0 = ch * 50, n1 = min(Ntok, n0 + 50);
    float s0 = 0.f, s1 = 0.f, s2 = 0.f;
    for (int n = n0; n < n1; ++n) {
        const float* row = x + ((size_t)b * Ntok + n) * Cdim;
        f16* orow = xa + ((size_t)b * Ttok + n) * Cdim;
        float v0 = row[t], v1 = row[t + 256], v2 = row[t + 512];
        s0 += v0; s1 += v1; s2 += v2;
        orow[t] = (f16)v0; orow[t + 256] = (f16)v1; orow[t + 512] = (f16)v2;
    }
    float* p = partial + ((size_t)b * 16 + ch) * Cdim;
    p[t] = s0; p[t + 256] = s1; p[t + 512] = s2;
}

__global__ void colmean_reduce(const float* __restrict__ partial, float* __restrict__ xh) {
    int b = blockIdx.x, t = threadIdx.x;
    #pragma unroll
    for (int i = 0; i < 3; ++i) {
        int c = t + i * 256;
        float s = 0.f;
        for (int ch = 0; ch < 16; ++ch) s += partial[((size_t)b * 16 + ch) * Cdim + c];
        xh[(size_t)b * Cdim + c] = s * (1.0f / (float)Ntok);
    }
}

// ------------- head tokens: proj + LN + GELU + pos -> xa rows [N..T) -------
__global__ void headtok_kernel(const float* __restrict__ xh, const float* __restrict__ htp_w,
                               const float* __restrict__ htp_b, const float* __restrict__ ln_g,
                               const float* __restrict__ ln_b, const float* __restrict__ pos,
                               f16* __restrict__ xa) {
    int blk = blockIdx.x;
    int b  = blk / (Hn * Hn);
    int rem = blk % (Hn * Hn);
    int h  = rem / Hn;
    int h2 = rem % Hn;
    int lane = threadIdx.x;
    int c = h2 * HD + lane;

    float acc = htp_b[c];
    const float* xrow = xh + (size_t)b * Cdim + h * HD;
    #pragma unroll 8
    for (int d = 0; d < HD; ++d) acc += xrow[d] * htp_w[(size_t)d * Cdim + c];

    float mu = wave_sum(acc) * (1.0f / 64.0f);
    float diff = acc - mu;
    float var = wave_sum(diff * diff) * (1.0f / 64.0f);
    float y = diff * rsqrtf(var + LN_EPS) * ln_g[lane] + ln_b[lane];
    float g = 0.5f * y * (1.0f + erff(y * 0.70710678118654752f));
    float v = g + pos[(size_t)h * Cdim + c];
    xa[((size_t)b * Ttok + Ntok + h) * Cdim + c] = (f16)v;
}

// ------------- W[K][N] -> W^T fp16 [N][K] (LDS tile transpose) -------------
__global__ void convert_wT(const float* __restrict__ W, f16* __restrict__ WT, int K, int N) {
    __shared__ float tile[32][33];
    int nt = blockIdx.x * 32, kt = blockIdx.y * 32;
    int tx = threadIdx.x & 31, ty = threadIdx.x >> 5;  // ty 0..7
    #pragma unroll
    for (int r = 0; r < 32; r += 8)
        tile[ty + r][tx] = W[(size_t)(kt + ty + r) * N + nt + tx];
    __syncthreads();
    #pragma unroll
    for (int r = 0; r < 32; r += 8) {
        int n = nt + ty + r, k = kt + tx;
        WT[(size_t)n * K + k] = (f16)tile[tx][ty + r];
    }
}

// ==================== MFMA fp16 GEMM =======================================
// C[M][N] = A[M][K] * W[K][N]; A row-major fp16, W transposed fp16 [N][K].
// 128x128 tile, 4 waves, BK=32, global_load_lds staging, k-grouped LDS.
// mode 0: fp32 out [M][N] (+bias). mode 1: scatter fp16 to (3,B,H,T,hd).
__global__ __launch_bounds__(256, 4)
void mfma_gemm(const f16* __restrict__ A, const f16* __restrict__ W,
               const float* __restrict__ bias, int M, int Nn, int mode,
               float* __restrict__ outF, f16* __restrict__ outH) {
    // per array: [4 kb][128 row][8 f16] = 8KB; 2 arrays (A, W); x2 dbuf = 32KB
    __shared__ __align__(16) f16 smem[2][2][4096];
    const int tid = threadIdx.x;
    const int w = tid >> 6, lane = tid & 63;
    const int lr = lane & 15, lg = lane >> 4;
    const int wr = w >> 1, wc = w & 1;
    const int mBase = blockIdx.x * 128, nBase = blockIdx.y * 128;

    const f16* src = (w < 2) ? A : W;
    const int arr = (w < 2) ? 0 : 1;
    const int kb0 = (w & 1) * 2;                    // waves 0,2: kb 0,1; waves 1,3: kb 2,3
    const int rowBase = (w < 2) ? mBase : nBase;
    const int rowMax  = (w < 2) ? (M - 1) : (Nn - 1);

    f32x4 acc[4][4];
    #pragma unroll
    for (int mi = 0; mi < 4; ++mi)
        #pragma unroll
        for (int ni = 0; ni < 4; ++ni) {
            acc[mi][ni][0] = 0.f; acc[mi][ni][1] = 0.f;
            acc[mi][ni][2] = 0.f; acc[mi][ni][3] = 0.f;
        }

    auto stage = [&](int buf, int k0) {
        #pragma unroll
        for (int kb = kb0; kb < kb0 + 2; ++kb) {
            #pragma unroll
            for (int half = 0; half < 2; ++half) {
                int row = min(rowBase + half * 64 + lane, rowMax);
                const f16* g = src + (size_t)row * Kdim + k0 + kb * 8;
                f16* l = &smem[buf][arr][kb * 1024 + half * 512];  // + lane*16B by HW
                __builtin_amdgcn_global_load_lds(
                    (const __attribute__((address_space(1))) void*)g,
                    (__attribute__((address_space(3))) void*)l, 16, 0, 0);
            }
        }
    };

    stage(0, 0);
    int cur = 0;
    const int NT = Kdim / 32;  // 24
    for (int t = 0; t < NT; ++t) {
        __syncthreads();
        if (t + 1 < NT) stage(cur ^ 1, (t + 1) * 32);
        const f16* AS = &smem[cur][0][0];
        const f16* WS = &smem[cur][1][0];
        half8 a[4], b[4];
        #pragma unroll
        for (int mi = 0; mi < 4; ++mi)
            a[mi] = *reinterpret_cast<const half8*>(&AS[lg * 1024 + (wr * 64 + mi * 16 + lr) * 8]);
        #pragma unroll
        for (int ni = 0; ni < 4; ++ni)
            b[ni] = *reinterpret_cast<const half8*>(&WS[lg * 1024 + (wc * 64 + ni * 16 + lr) * 8]);
        #pragma unroll
        for (int mi = 0; mi < 4; ++mi)
            #pragma unroll
            for (int ni = 0; ni < 4; ++ni)
                acc[mi][ni] = __builtin_amdgcn_mfma_f32_16x16x32_f16(a[mi], b[ni], acc[mi][ni], 0, 0, 0);
        cur ^= 1;
    }

    #pragma unroll
    for (int ni = 0; ni < 4; ++ni) {
        int gn = nBase + wc * 64 + ni * 16 + lr;
        if (mode == 0) {
            float bv = bias ? bias[gn] : 0.f;
            #pragma unroll
            for (int mi = 0; mi < 4; ++mi)
                #pragma unroll
                for (int r = 0; r < 4; ++r) {
                    int gm = mBase + wr * 64 + mi * 16 + lg * 4 + r;
                    if (gm < M) outF[(size_t)gm * Nn + gn] = acc[mi][ni][r] + bv;
                }
        } else {
            int s = gn / Cdim;
            int hc = gn - s * Cdim;
            int h = hc >> 6, d = hc & 63;
            #pragma unroll
            for (int mi = 0; mi < 4; ++mi)
                #pragma unroll
                for (int r = 0; r < 4; ++r) {
                    int gm = mBase + wr * 64 + mi * 16 + lg * 4 + r;
                    if (gm < M) {
                        int bb = gm / Ttok, tt = gm - bb * Ttok;
                        size_t o = (((size_t)(s * Bsz + bb) * Hn + h) * Ttok + tt) * HD + d;
                        outH[o] = (f16)acc[mi][ni][r];
                    }
                }
        }
    }
}

// ==================== MFMA fp16 flash attention ============================
__global__ __launch_bounds__(256, 4)
void flash_attn_kernel(const f16* __restrict__ Qb, const f16* __restrict__ Kb,
                       const f16* __restrict__ Vb, f16* __restrict__ ao) {
    __shared__ __align__(16) f16 KS[64 * 64];       // [key][dim] swizzled
    __shared__ __align__(16) f16 VS[64 * 64];       // [dim][key] swizzled (V^T)
    __shared__ __align__(16) f16 PS[4][16 * 64];    // per-wave P [row][key] swizzled

    const int nQT = 13;
    int bh = blockIdx.x / nQT;
    int qt = blockIdx.x % nQT;
    int tid = threadIdx.x;
    int w = tid >> 6, lane = tid & 63;
    int lr = lane & 15, lg = lane >> 4;
    size_t base = (size_t)bh * Ttok * HD;

    half8 qf[2];
    {
        int qrow = qt * 64 + w * 16 + lr;
        int crow = min(qrow, Ttok - 1);
        #pragma unroll
        for (int kf = 0; kf < 2; ++kf)
            qf[kf] = *reinterpret_cast<const half8*>(Qb + base + (size_t)crow * HD + kf * 32 + lg * 8);
    }

    f32x4 O[4];
    #pragma unroll
    for (int nt = 0; nt < 4; ++nt) { O[nt][0]=0.f; O[nt][1]=0.f; O[nt][2]=0.f; O[nt][3]=0.f; }
    float mrow[4] = {-1e30f, -1e30f, -1e30f, -1e30f};
    float lrow[4] = {0.f, 0.f, 0.f, 0.f};

    for (int kt = 0; kt < 13; ++kt) {
        __syncthreads();
        {
            int key = tid >> 2;
            int dseg = (tid & 3) * 16;
            int gk = kt * 64 + key;
            int slotK = SW(key);
            if (gk < Ttok) {
                const f16* kp = Kb + base + (size_t)gk * HD + dseg;
                const f16* vp = Vb + base + (size_t)gk * HD + dseg;
                #pragma unroll
                for (int c = 0; c < 2; ++c)
                    *reinterpret_cast<half8*>(&KS[(key * 64 + dseg + c * 8) ^ slotK]) =
                        *reinterpret_cast<const half8*>(kp + c * 8);
                half8 v8[2];
                #pragma unroll
                for (int c = 0; c < 2; ++c)
                    v8[c] = *reinterpret_cast<const half8*>(vp + c * 8);
                #pragma unroll
                for (int c = 0; c < 2; ++c)
                    #pragma unroll
                    for (int j = 0; j < 8; ++j) {
                        int dim = dseg + c * 8 + j;
                        VS[(dim * 64 + key) ^ SW(dim)] = v8[c][j];
                    }
            } else {
                half8 z = {0, 0, 0, 0, 0, 0, 0, 0};
                #pragma unroll
                for (int c = 0; c < 2; ++c)
                    *reinterpret_cast<half8*>(&KS[(key * 64 + dseg + c * 8) ^ slotK]) = z;
                #pragma unroll
                for (int i = 0; i < 16; ++i) {
                    int dim = dseg + i;
                    VS[(dim * 64 + key) ^ SW(dim)] = (f16)0.f;
                }
            }
        }
        __syncthreads();

        f32x4 s[4];
        #pragma unroll
        for (int nt = 0; nt < 4; ++nt) { s[nt][0]=0.f; s[nt][1]=0.f; s[nt][2]=0.f; s[nt][3]=0.f; }
        #pragma unroll
        for (int kf = 0; kf < 2; ++kf) {
            #pragma unroll
            for (int nt = 0; nt < 4; ++nt) {
                int key = nt * 16 + lr;
                int d0 = kf * 32 + lg * 8;
                half8 k8 = *reinterpret_cast<const half8*>(&KS[(key * 64 + d0) ^ SW(key)]);
                s[nt] = __builtin_amdgcn_mfma_f32_16x16x32_f16(qf[kf], k8, s[nt], 0, 0, 0);
            }
        }
        int kbase = kt * 64;
        #pragma unroll
        for (int nt = 0; nt < 4; ++nt) {
            bool invalid = (kbase + nt * 16 + lr) >= Ttok;
            #pragma unroll
            for (int r = 0; r < 4; ++r) {
                float sv = s[nt][r] * 0.125f;
                s[nt][r] = invalid ? -1e30f : sv;
            }
        }
        float rmax[4];
        #pragma unroll
        for (int r = 0; r < 4; ++r)
            rmax[r] = fmaxf(fmaxf(s[0][r], s[1][r]), fmaxf(s[2][r], s[3][r]));
        #pragma unroll
        for (int off = 1; off < 16; off <<= 1)
            #pragma unroll
            for (int r = 0; r < 4; ++r)
                rmax[r] = fmaxf(rmax[r], __shfl_xor(rmax[r], off, 64));
        float corr[4];
        #pragma unroll
        for (int r = 0; r < 4; ++r) {
            float mn = fmaxf(mrow[r], rmax[r]);
            corr[r] = __expf(mrow[r] - mn);
            mrow[r] = mn;
        }
        float psum[4] = {0.f, 0.f, 0.f, 0.f};
        #pragma unroll
        for (int nt = 0; nt < 4; ++nt)
            #pragma unroll
            for (int r = 0; r < 4; ++r) {
                float p = __expf(s[nt][r] - mrow[r]);
                s[nt][r] = p;
                psum[r] += p;
            }
        #pragma unroll
        for (int off = 1; off < 16; off <<= 1)
            #pragma unroll
            for (int r = 0; r < 4; ++r)
                psum[r] += __shfl_xor(psum[r], off, 64);
        #pragma unroll
        for (int r = 0; r < 4; ++r) lrow[r] = lrow[r] * corr[r] + psum[r];
        #pragma unroll
        for (int nt = 0; nt < 4; ++nt)
            #pragma unroll
            for (int r = 0; r < 4; ++r) O[nt][r] *= corr[r];
        f16* Pw = &PS[w][0];
        #pragma unroll
        for (int nt = 0; nt < 4; ++nt)
            #pragma unroll
            for (int r = 0; r < 4; ++r) {
                int row = lg * 4 + r;
                int col = nt * 16 + lr;
                Pw[(row * 64 + col) ^ SW(row)] = (f16)s[nt][r];
            }
        half8 pa[2];
        #pragma unroll
        for (int kf = 0; kf < 2; ++kf)
            pa[kf] = *reinterpret_cast<const half8*>(&Pw[(lr * 64 + kf * 32 + lg * 8) ^ SW(lr)]);
        #pragma unroll
        for (int kf = 0; kf < 2; ++kf) {
            #pragma unroll
            for (int nt = 0; nt < 4; ++nt) {
                int dim = nt * 16 + lr;
                int k0 = kf * 32 + lg * 8;
                half8 v8 = *reinterpret_cast<const half8*>(&VS[(dim * 64 + k0) ^ SW(dim)]);
                O[nt] = __builtin_amdgcn_mfma_f32_16x16x32_f16(pa[kf], v8, O[nt], 0, 0, 0);
            }
        }
    }

    int b = bh / Hn, h = bh % Hn;
    #pragma unroll
    for (int r = 0; r < 4; ++r) {
        int qrow = qt * 64 + w * 16 + lg * 4 + r;
        if (qrow >= Ttok) continue;
        float inv = 1.0f / lrow[r];
        #pragma unroll
        for (int nt = 0; nt < 4; ++nt)
            ao[((size_t)b * Ttok + qrow) * Cdim + h * HD + nt * 16 + lr] = (f16)(O[nt][r] * inv);
    }
}

// -------------------- epilogue: cls row + copy rows 1..N-1 -----------------
__global__ void cls_kernel(const float* __restrict__ out_full, float* __restrict__ out) {
    int b = blockIdx.x, t = threadIdx.x;
    #pragma unroll
    for (int i = 0; i < 3; ++i) {
        int c = t + i * 256;
        float s = out_full[((size_t)b * Ttok) * Cdim + c];
        float hs = 0.f;
        #pragma unroll
        for (int h = 0; h < Hn; ++h)
            hs += out_full[((size_t)b * Ttok + Ntok + h) * Cdim + c];
        out[((size_t)b * Ntok) * Cdim + c] = s + hs * (1.0f / (float)Hn);
    }
}

__global__ void final_copy(const float4* __restrict__ out_full, float4* __restrict__ out) {
    const int C4 = Cdim / 4;
    int total = Bsz * (Ntok - 1) * C4;
    for (int i = blockIdx.x * blockDim.x + threadIdx.x; i < total; i += gridDim.x * blockDim.x) {
        int row = i / C4, c4 = i - row * C4;
        int b = row / (Ntok - 1), n = 1 + row - b * (Ntok - 1);
        out[((size_t)b * Ntok + n) * C4 + c4] = out_full[((size_t)b * Ttok + n) * C4 + c4];
    }
}

extern "C" void kernel_launch(void* const* d_in, const int* in_sizes, int n_in,
                              void* d_out, int out_size, void* d_ws, size_t ws_size,
                              hipStream_t stream) {
    const float* x      = (const float*)d_in[0];
    const float* qkv_w  = (const float*)d_in[1];
    const float* proj_w = (const float*)d_in[2];
    const float* proj_b = (const float*)d_in[3];
    const float* htp_w  = (const float*)d_in[4];
    const float* htp_b  = (const float*)d_in[5];
    const float* ln_g   = (const float*)d_in[6];
    const float* ln_b   = (const float*)d_in[7];
    const float* pos    = (const float*)d_in[8];
    float* out = (float*)d_out;

    const size_t MC = (size_t)Mrows * Cdim;        // 9,793,536
    const size_t WQ = (size_t)K3C * Kdim;          // 1,769,472
    const size_t WP = (size_t)Cdim * Kdim;         // 589,824

    f16* qkv   = (f16*)d_ws;                       // 3*MC f16 (Q,K,V)
    f16* xa    = qkv + 3 * MC;                     // MC f16 (input; later attnout)
    f16* wq    = xa + MC;                          // WQ f16  (qkv_w^T)
    f16* wp    = wq + WQ;                          // WP f16  (proj_w^T)
    float* partial = (float*)(wp + WP);            // B*16*C fp32
    float* xh      = partial + (size_t)Bsz * 16 * Cdim;  // B*C fp32
    float* out_full = (float*)qkv;                 // reuse qkv region after attn (fp32 B*T*C)

    prep_x<<<dim3(Bsz, 16), 256, 0, stream>>>(x, xa, partial);
    colmean_reduce<<<Bsz, 256, 0, stream>>>(partial, xh);
    headtok_kernel<<<Bsz * Hn * Hn, 64, 0, stream>>>(xh, htp_w, htp_b, ln_g, ln_b, pos, xa);
    convert_wT<<<dim3(K3C / 32, Kdim / 32), 256, 0, stream>>>(qkv_w, wq, Kdim, K3C);
    convert_wT<<<dim3(Cdim / 32, Kdim / 32), 256, 0, stream>>>(proj_w, wp, Kdim, Cdim);

    mfma_gemm<<<dim3((Mrows + 127) / 128, K3C / 128), 256, 0, stream>>>(
        xa, wq, nullptr, Mrows, K3C, 1, nullptr, qkv);

    flash_attn_kernel<<<Bsz * Hn * 13, 256, 0, stream>>>(
        qkv, qkv + MC, qkv + 2 * MC, xa);

    mfma_gemm<<<dim3((Mrows + 127) / 128, Cdim / 128), 256, 0, stream>>>(
        xa, wp, proj_b, Mrows, Cdim, 0, out_full, nullptr);

    cls_kernel<<<Bsz, 256, 0, stream>>>(out_full, out);
    final_copy<<<2048, 256, 0, stream>>>((const float4*)out_full, (float4*)out);
}